// Round 25
// baseline (132.590 us; speedup 1.0000x reference)
//
#include <hip/hip_runtime.h>
#include <hip/hip_bf16.h>

// Problem constants
#define DM     128
#define DSTATE 16
#define DINNER 256
#define CCONV  16
#define NEIGH  27
#define DSEQ   432   // CCONV * NEIGH
#define DTRANK 14
#define LVOL   4096  // 16*16*16
#define BATCH  2
#define NTOK   8192  // BATCH * LVOL

typedef __attribute__((ext_vector_type(8))) unsigned short ushort8_t;
typedef __attribute__((ext_vector_type(8))) short short8_t;   // bf16x8 MFMA frag
typedef __attribute__((ext_vector_type(4))) float f32x4_t;    // MFMA acc

__device__ __forceinline__ float bf2f(unsigned short u) {
    union { unsigned int i; float f; } v; v.i = ((unsigned int)u) << 16; return v.f;
}
__device__ __forceinline__ unsigned short f2b(float f) {
    __hip_bfloat16 hb = __float2bfloat16(f);
    return *(unsigned short*)&hb;
}

// ---------------------------------------------------------------- merged weight prep
// wib bf16 [512][128]; wfb bf16 [256][448]; wob bf16 [128][256];
// wxpb bf16 [48][448] (x_proj_w zero-padded)
__global__ void k_wprep(const float* __restrict__ w_in, const float* __restrict__ w_fold,
                        const float* __restrict__ w_out, const float* __restrict__ x_proj_w,
                        unsigned short* __restrict__ wib, unsigned short* __restrict__ wfb,
                        unsigned short* __restrict__ wob, unsigned short* __restrict__ wxpb) {
    int idx = blockIdx.x * 256 + threadIdx.x;
    if (idx < 65536) {
        wib[idx] = f2b(w_in[idx]);
    } else if (idx < 65536 + 114688) {
        int local = idx - 65536;
        int o = local / 448, dk = local - o * 448;
        wfb[local] = (dk < 432) ? f2b(w_fold[o * 432 + dk]) : (unsigned short)0;
    } else if (idx < 65536 + 114688 + 32768) {
        int local = idx - 65536 - 114688;
        wob[local] = f2b(w_out[local]);
    } else if (idx < 65536 + 114688 + 32768 + 21504) {
        int local = idx - 65536 - 114688 - 32768;
        int c = local / 448, dk = local - c * 448;
        wxpb[local] = (c < 46 && dk < 432) ? f2b(x_proj_w[c * 432 + dk]) : (unsigned short)0;
    }
}

// ---------------------------------------------------------------- in-proj via MFMA (R24 verified)
__global__ void k_inproj(const float* __restrict__ x, const unsigned short* __restrict__ wib,
                         float* __restrict__ xpt, float* __restrict__ zbufT) {
    int t = threadIdx.x;          // 0..255
    int w = t >> 6, l = t & 63;
    int lc = l & 15, lr = l >> 4;
    int tokbase = blockIdx.x * 32;
    int b = tokbase >> 12, lbase = tokbase & 4095;

    __shared__ unsigned short xsT[32][136];   // [tok][k] bf16, +8 pad

    for (int idx = t; idx < 1024; idx += 256) {
        int row = idx >> 5, cb = idx & 31;
        float4 v = *(const float4*)(x + (size_t)(tokbase + row) * 128 + cb * 4);
        unsigned int p0 = (unsigned)f2b(v.x) | ((unsigned)f2b(v.y) << 16);
        unsigned int p1 = (unsigned)f2b(v.z) | ((unsigned)f2b(v.w) << 16);
        *(unsigned int*)&xsT[row][cb * 4]     = p0;
        *(unsigned int*)&xsT[row][cb * 4 + 2] = p1;
    }
    __syncthreads();

#pragma unroll
    for (int mi = 0; mi < 8; mi++) {
        int mt = w * 8 + mi;      // 0..31 (0..15 xp, 16..31 z)
#pragma unroll
        for (int nt = 0; nt < 2; nt++) {
            f32x4_t acc = (f32x4_t){0.f, 0.f, 0.f, 0.f};
#pragma unroll
            for (int ks = 0; ks < 4; ks++) {
                int kb = ks * 32 + lr * 8;
                short8_t bfr = *(const short8_t*)&xsT[nt * 16 + lc][kb];
                short8_t afr = *(const short8_t*)(wib + (size_t)(mt * 16 + lc) * 128 + kb);
                acc = __builtin_amdgcn_mfma_f32_16x16x32_bf16(afr, bfr, acc, 0, 0, 0);
            }
            int ltok = lbase + nt * 16 + lc;
            int ch = mt * 16 + lr * 4;
            float* dst = (mt < 16)
                ? (xpt   + (size_t)(b * 256 + ch)       * 4096 + ltok)
                : (zbufT + (size_t)(b * 256 + ch - 256) * 4096 + ltok);
#pragma unroll
            for (int r = 0; r < 4; r++)
                dst[(size_t)r * 4096] = acc[r];
        }
    }
}

// ---------------------------------------------------------------- grouped conv3d + SiLU
__global__ void k_conv(const float* __restrict__ xpt, const float* __restrict__ conv_w,
                       const float* __restrict__ conv_b, float* __restrict__ xc) {
    int t = threadIdx.x;
    int tok = blockIdx.x * 256 + t;
    int co = blockIdx.y;
    int b = tok >> 12, l = tok & 4095;
    int d0 = l >> 8, h0 = (l >> 4) & 15, w0 = l & 15;
    int nbo[27];
#pragma unroll
    for (int t27 = 0; t27 < 27; t27++) {
        int di = t27 / 9 - 1, dj = (t27 / 3) % 3 - 1, dk = t27 % 3 - 1;
        int zd = d0 + di, zh = h0 + dj, zw = w0 + dk;
        nbo[t27] = ((unsigned)zd > 15u || (unsigned)zh > 15u || (unsigned)zw > 15u)
                   ? -1 : ((zd << 8) + (zh << 4) + zw);
    }
    const float* xb = xpt + (size_t)(b * 256 + co * 16) * 4096;
    const float* wr = conv_w + co * 432;   // uniform -> s_load
    float acc0 = conv_b[co], acc1 = 0.f;
    for (int t27 = 0; t27 < 27; t27++) {
        int o = nbo[t27];
        if (o >= 0) {
#pragma unroll
            for (int q = 0; q < 16; q += 2) {
                acc0 += xb[q * 4096 + o]       * wr[q * 27 + t27];
                acc1 += xb[(q + 1) * 4096 + o] * wr[(q + 1) * 27 + t27];
            }
        }
    }
    float acc = acc0 + acc1;
    acc = acc / (1.f + __expf(-acc));  // SiLU
    xc[(b * 16 + co) * 4096 + l] = acc;
}

// ---------------------------------------------------------------- x_dbl via MFMA (R23 verified)
__global__ void k_xdbl(const float* __restrict__ xc, const unsigned short* __restrict__ wxpb,
                       float* __restrict__ dts, __hip_bfloat16* __restrict__ bc2) {
    int t = threadIdx.x;          // 0..255, 4 waves
    int w = t >> 6, l = t & 63;
    int lc = l & 15, lr = l >> 4;
    int tokbase = blockIdx.x * 32;
    int b = tokbase >> 12, lbase = tokbase & 4095;

    __shared__ unsigned short xsT[32][456];

    for (int p = t; p < 432; p += 256) {
        int ch = p / 27, tap = p - ch * 27;
        int di = tap / 9 - 1, dj = (tap / 3) % 3 - 1, dk = tap % 3 - 1;
        const float* xr = xc + (size_t)(b * 16 + ch) * 4096;
        for (int tk = 0; tk < 32; tk++) {
            int ll = lbase + tk;
            int zd = (ll >> 8) + di, zh = ((ll >> 4) & 15) + dj, zw = (ll & 15) + dk;
            float v = (((unsigned)zd <= 15u) && ((unsigned)zh <= 15u) && ((unsigned)zw <= 15u))
                      ? xr[(zd << 8) + (zh << 4) + zw] : 0.f;
            xsT[tk][p] = f2b(v);
        }
    }
    for (int idx = t; idx < 16 * 32; idx += 256)
        xsT[idx & 31][432 + (idx >> 5)] = 0;
    __syncthreads();

    for (int ti = w; ti < 6; ti += 4) {
        int mt = ti % 3, nt = ti / 3;
        f32x4_t acc = (f32x4_t){0.f, 0.f, 0.f, 0.f};
        for (int ks = 0; ks < 14; ks++) {
            int kb = ks * 32 + lr * 8;
            short8_t bfr = *(const short8_t*)&xsT[nt * 16 + lc][kb];
            short8_t afr = *(const short8_t*)(wxpb + (size_t)(mt * 16 + lc) * 448 + kb);
            acc = __builtin_amdgcn_mfma_f32_16x16x32_bf16(afr, bfr, acc, 0, 0, 0);
        }
        int ltok = lbase + nt * 16 + lc;
#pragma unroll
        for (int r = 0; r < 4; r++) {
            int c = mt * 16 + lr * 4 + r;
            if (c < 14)
                dts[(size_t)(b * 14 + c) * 4096 + ltok] = acc[r];
            else if (c < 46)
                bc2[(size_t)(b * 32 + (c - 14)) * 4096 + ltok] = __float2bfloat16(acc[r]);
        }
    }
}

// ---------------------------------------------------------------- selective scan (+ fused delta)
// 256 thr/block (4 waves), thread t owns l in [t*16, t*16+16) (one full w-row).
// All 864 blocks co-resident at 4 blocks/CU ((256,2) -> 128-VGPR cap).
// Monoid (sdt, Bp[16]) fast path (17 shuffled vals/step, amortized over 2x l);
// exact fallback kept. bf16 y output.
__global__ __launch_bounds__(256, 2) void k_scan(
        const float* __restrict__ xc, const float* __restrict__ dts,
        const unsigned short* __restrict__ bc2, const float* __restrict__ dt_w,
        const float* __restrict__ dt_b, const float* __restrict__ A_logs,
        const float* __restrict__ Ds, unsigned short* __restrict__ y) {
    int bd = blockIdx.x;
    int b = bd / 432, dch = bd % 432;
    int t = threadIdx.x;               // 0..255
    int lane = t & 63, wv = t >> 6;    // 4 waves

    bool intA = true;
#pragma unroll
    for (int n = 0; n < 16; n++) {
        float An = -__expf(A_logs[dch * 16 + n]);
        intA = intA && (fabsf(An + (float)(n + 1)) < 1e-3f);
    }
    float Dskip = Ds[dch];

    int cch = dch / 27, t27 = dch % 27;
    int di = t27 / 9 - 1, dj = (t27 / 3) % 3 - 1, dk = t27 % 3 - 1;

    // ---- fused delta -> dtv[16]
    float dtv[16];
    {
        float bias = dt_b[dch];
#pragma unroll
        for (int i = 0; i < 16; i++) dtv[i] = bias;
        const float* dsb = dts + (size_t)(b * 14) * 4096 + t * 16;
#pragma unroll
        for (int r = 0; r < 14; r++) {
            float w = dt_w[dch * 14 + r];
            const float4* dp = (const float4*)(dsb + (size_t)r * 4096);
#pragma unroll
            for (int q = 0; q < 4; q++) {
                float4 d4 = dp[q];
                dtv[4 * q + 0] += d4.x * w;
                dtv[4 * q + 1] += d4.y * w;
                dtv[4 * q + 2] += d4.z * w;
                dtv[4 * q + 3] += d4.w * w;
            }
        }
#pragma unroll
        for (int i = 0; i < 16; i++)
            dtv[i] = (dtv[i] > 15.f) ? dtv[i] : log1pf(__expf(dtv[i]));
    }

    // ---- u gather (one w-row); ys = Dskip*u; av; sdt. dtv dead after this.
    int zd = (t >> 4) + di, zh = (t & 15) + dj;
    bool rowok = ((unsigned)zd <= 15u) && ((unsigned)zh <= 15u);
    const float* xr = xc + (size_t)(b * 16 + cch) * 4096 + (zd << 8) + (zh << 4);
    float dtu[16], ys[16], av[16];
#pragma unroll
    for (int i = 0; i < 16; i++) {
        int zw = i + dk;
        float u = (rowok && (unsigned)zw <= 15u) ? xr[zw] : 0.f;
        dtu[i] = dtv[i] * u;
        ys[i] = Dskip * u;
    }
    float sdt = 0.f;
#pragma unroll
    for (int i = 0; i < 16; i++) sdt += dtv[i];
    if (intA) {
#pragma unroll
        for (int i = 0; i < 16; i++) av[i] = __expf(-dtv[i]);
    } else {
#pragma unroll
        for (int i = 0; i < 16; i++) av[i] = dtv[i] * 1.44269504f;  // log2 scale
    }

    const unsigned short* bcb = bc2 + (size_t)(b * 32) * 4096 + t * 16;

    __shared__ float waggA[4][16], waggB[4][16];
    __shared__ float waggS[4];

    float h[16];

    if (intA) {
        // ======================= FAST PATH =======================
        float aw[16];
#pragma unroll
        for (int i = 0; i < 16; i++) aw[i] = av[i];

        float Bp[16];
#pragma unroll
        for (int n = 0; n < 16; n++) {
            ushort8_t B0 = *(const ushort8_t*)(bcb + (size_t)n * 4096);
            ushort8_t B1 = *(const ushort8_t*)(bcb + (size_t)n * 4096 + 8);
            float bp = 0.f;
#pragma unroll
            for (int i = 0; i < 8; i++)
                bp = aw[i] * bp + dtu[i] * bf2f(B0[i]);
#pragma unroll
            for (int i = 8; i < 16; i++)
                bp = aw[i] * bp + dtu[i] * bf2f(B1[i - 8]);
            Bp[n] = bp;
            if (n < 15) {
#pragma unroll
                for (int i = 0; i < 16; i++) aw[i] *= av[i];
            }
        }

        // wave-level inclusive scan over (sdt, Bp[16])
#pragma unroll
        for (int s = 1; s < 64; s <<= 1) {
            float psdt = __shfl_up(sdt, s, 64);
            float pl = __expf(-sdt);   // later-segment decay base (pre-update)
            float pb[16];
#pragma unroll
            for (int n = 0; n < 16; n++) pb[n] = __shfl_up(Bp[n], s, 64);
            if (lane >= s) {
                float pw = pl;
#pragma unroll
                for (int n = 0; n < 16; n++) {
                    Bp[n] = pw * pb[n] + Bp[n];
                    pw *= pl;
                }
                sdt += psdt;
            }
        }

        // cross-wave prefix (4 waves)
        if (lane == 63) {
            waggS[wv] = sdt;
#pragma unroll
            for (int n = 0; n < 16; n++) waggB[wv][n] = Bp[n];
        }
        __syncthreads();

        float exsdt = __shfl_up(sdt, 1, 64);
        float exB[16];
#pragma unroll
        for (int n = 0; n < 16; n++) exB[n] = __shfl_up(Bp[n], 1, 64);
        if (lane == 0) {
            exsdt = 0.f;
#pragma unroll
            for (int n = 0; n < 16; n++) exB[n] = 0.f;
        }
        float WB[16];
#pragma unroll
        for (int n = 0; n < 16; n++) WB[n] = 0.f;
        for (int ww = 0; ww < wv; ww++) {
            float plw = __expf(-waggS[ww]);
            float pww = plw;
#pragma unroll
            for (int n = 0; n < 16; n++) {
                WB[n] = pww * WB[n] + waggB[ww][n];
                pww *= plw;
            }
        }
        float pex = __expf(-exsdt);
        float pwx = pex;
#pragma unroll
        for (int n = 0; n < 16; n++) {
            h[n] = pwx * WB[n] + exB[n];
            pwx *= pex;
        }
    } else {
        // ======================= FALLBACK (exact) =======================
        float Ap[16], Bp[16];
        float s2 = sdt * 1.44269504f;
#pragma unroll
        for (int n = 0; n < 16; n++) {
            float An = -__expf(A_logs[dch * 16 + n]);
            ushort8_t B0 = *(const ushort8_t*)(bcb + (size_t)n * 4096);
            ushort8_t B1 = *(const ushort8_t*)(bcb + (size_t)n * 4096 + 8);
            float bp = 0.f;
#pragma unroll
            for (int i = 0; i < 8; i++) {
                float a = exp2f(av[i] * An);
                bp = a * bp + dtu[i] * bf2f(B0[i]);
            }
#pragma unroll
            for (int i = 8; i < 16; i++) {
                float a = exp2f(av[i] * An);
                bp = a * bp + dtu[i] * bf2f(B1[i - 8]);
            }
            Ap[n] = exp2f(s2 * An);
            Bp[n] = bp;
        }
#pragma unroll
        for (int s = 1; s < 64; s <<= 1) {
#pragma unroll
            for (int n = 0; n < 16; n++) {
                float pa = __shfl_up(Ap[n], s, 64);
                float pb = __shfl_up(Bp[n], s, 64);
                if (lane >= s) {
                    Bp[n] = Ap[n] * pb + Bp[n];
                    Ap[n] *= pa;
                }
            }
        }
        if (lane == 63) {
#pragma unroll
            for (int n = 0; n < 16; n++) { waggA[wv][n] = Ap[n]; waggB[wv][n] = Bp[n]; }
        }
        __syncthreads();
#pragma unroll
        for (int n = 0; n < 16; n++) {
            float exA = __shfl_up(Ap[n], 1, 64);
            float exB = __shfl_up(Bp[n], 1, 64);
            if (lane == 0) { exA = 1.f; exB = 0.f; }
            float WB = 0.f;
            for (int ww = 0; ww < wv; ww++)
                WB = waggA[ww][n] * WB + waggB[ww][n];
            h[n] = exA * WB + exB;
        }
    }

    // ---- pass 2: rescan with incoming state
    if (intA) {
        float aw[16];
#pragma unroll
        for (int i = 0; i < 16; i++) aw[i] = av[i];
#pragma unroll
        for (int n = 0; n < 16; n++) {
            ushort8_t B0 = *(const ushort8_t*)(bcb + (size_t)n * 4096);
            ushort8_t B1 = *(const ushort8_t*)(bcb + (size_t)n * 4096 + 8);
            ushort8_t C0 = *(const ushort8_t*)(bcb + (size_t)(16 + n) * 4096);
            ushort8_t C1 = *(const ushort8_t*)(bcb + (size_t)(16 + n) * 4096 + 8);
            float hn = h[n];
#pragma unroll
            for (int i = 0; i < 8; i++) {
                hn = aw[i] * hn + dtu[i] * bf2f(B0[i]);
                ys[i] += hn * bf2f(C0[i]);
            }
#pragma unroll
            for (int i = 8; i < 16; i++) {
                hn = aw[i] * hn + dtu[i] * bf2f(B1[i - 8]);
                ys[i] += hn * bf2f(C1[i - 8]);
            }
            if (n < 15) {
#pragma unroll
                for (int i = 0; i < 16; i++) aw[i] *= av[i];
            }
        }
    } else {
#pragma unroll
        for (int n = 0; n < 16; n++) {
            float An = -__expf(A_logs[dch * 16 + n]);
            ushort8_t B0 = *(const ushort8_t*)(bcb + (size_t)n * 4096);
            ushort8_t B1 = *(const ushort8_t*)(bcb + (size_t)n * 4096 + 8);
            ushort8_t C0 = *(const ushort8_t*)(bcb + (size_t)(16 + n) * 4096);
            ushort8_t C1 = *(const ushort8_t*)(bcb + (size_t)(16 + n) * 4096 + 8);
            float hn = h[n];
#pragma unroll
            for (int i = 0; i < 8; i++) {
                float a = exp2f(av[i] * An);
                hn = a * hn + dtu[i] * bf2f(B0[i]);
                ys[i] += hn * bf2f(C0[i]);
            }
#pragma unroll
            for (int i = 8; i < 16; i++) {
                float a = exp2f(av[i] * An);
                hn = a * hn + dtu[i] * bf2f(B1[i - 8]);
                ys[i] += hn * bf2f(C1[i - 8]);
            }
        }
    }

    // ---- store y as bf16 (two 16B stores)
    unsigned short* yo = y + (size_t)(b * 432 + dch) * 4096 + t * 16;
    ushort8_t o0, o1;
#pragma unroll
    for (int i = 0; i < 8; i++) { o0[i] = f2b(ys[i]); o1[i] = f2b(ys[8 + i]); }
    *(ushort8_t*)yo       = o0;
    *(ushort8_t*)(yo + 8) = o1;
}

// ---------------------------------------------------------------- MFMA tail (R22/R24 verified)
__global__ void k_tail(const unsigned short* __restrict__ y, const float* __restrict__ zbufT,
                       const unsigned short* __restrict__ wfb, const float* __restrict__ ln_g,
                       const float* __restrict__ ln_b, const unsigned short* __restrict__ wob,
                       float* __restrict__ out) {
    int t = threadIdx.x;          // 0..255
    int w = t >> 6;               // wave 0..3
    int l = t & 63;               // lane
    int lc = l & 15;              // token (B col / D col)
    int lr = l >> 4;              // k-group / D row-group
    int tokbase = blockIdx.x * 16;
    int b = tokbase >> 12, lbase = tokbase & 4095;

    __shared__ unsigned short Yt[16][456];
    __shared__ unsigned short Pt[16][264];
    __shared__ float red[4][16][2];

    for (int d = t; d < 448; d += 256) {
        if (d < 432) {
            const unsigned short* yr = y + (size_t)(b * 432 + d) * 4096 + lbase;
            ushort8_t v0 = *(const ushort8_t*)(yr);
            ushort8_t v1 = *(const ushort8_t*)(yr + 8);
#pragma unroll
            for (int j = 0; j < 8; j++) { Yt[j][d] = v0[j]; Yt[8 + j][d] = v1[j]; }
        } else {
#pragma unroll
            for (int j = 0; j < 16; j++) Yt[j][d] = 0;
        }
    }
    __syncthreads();

    f32x4_t acc[4];
#pragma unroll
    for (int m = 0; m < 4; m++) acc[m] = (f32x4_t){0.f, 0.f, 0.f, 0.f};
    for (int ks = 0; ks < 14; ks++) {
        int kb = ks * 32 + lr * 8;
        short8_t bf = *(const short8_t*)&Yt[lc][kb];
#pragma unroll
        for (int m = 0; m < 4; m++) {
            int outrow = (4 * w + m) * 16 + lc;
            short8_t af = *(const short8_t*)(wfb + (size_t)outrow * 448 + kb);
            acc[m] = __builtin_amdgcn_mfma_f32_16x16x32_bf16(af, bf, acc[m], 0, 0, 0);
        }
    }

    {
        float s = 0.f, s2 = 0.f;
#pragma unroll
        for (int m = 0; m < 4; m++) {
#pragma unroll
            for (int r = 0; r < 4; r++) { float v = acc[m][r]; s += v; s2 += v * v; }
        }
        s  += __shfl_xor(s, 16, 64);  s2 += __shfl_xor(s2, 16, 64);
        s  += __shfl_xor(s, 32, 64);  s2 += __shfl_xor(s2, 32, 64);
        if (l < 16) { red[w][l][0] = s; red[w][l][1] = s2; }
    }
    __syncthreads();
    float mu, rs;
    {
        float ts  = red[0][lc][0] + red[1][lc][0] + red[2][lc][0] + red[3][lc][0];
        float ts2 = red[0][lc][1] + red[1][lc][1] + red[2][lc][1] + red[3][lc][1];
        mu = ts * (1.f / 256.f);
        float var = ts2 * (1.f / 256.f) - mu * mu;
        rs = rsqrtf(var + 1e-5f);
    }

#pragma unroll
    for (int m = 0; m < 4; m++) {
#pragma unroll
        for (int r = 0; r < 4; r++) {
            int oidx = (4 * w + m) * 16 + lr * 4 + r;
            float g = ln_g[oidx], be = ln_b[oidx];
            float zv = zbufT[(size_t)(b * 256 + oidx) * 4096 + lbase + lc];
            float sz = zv / (1.f + __expf(-zv));
            float p = ((acc[m][r] - mu) * rs * g + be) * sz;
            Pt[lc][oidx] = f2b(p);
        }
    }
    __syncthreads();

    f32x4_t oacc[2];
    oacc[0] = (f32x4_t){0.f, 0.f, 0.f, 0.f};
    oacc[1] = (f32x4_t){0.f, 0.f, 0.f, 0.f};
    for (int ks = 0; ks < 8; ks++) {
        int kb = ks * 32 + lr * 8;
        short8_t bf = *(const short8_t*)&Pt[lc][kb];
#pragma unroll
        for (int m = 0; m < 2; m++) {
            int orow = (2 * w + m) * 16 + lc;
            short8_t af = *(const short8_t*)(wob + (size_t)orow * 256 + kb);
            oacc[m] = __builtin_amdgcn_mfma_f32_16x16x32_bf16(af, bf, oacc[m], 0, 0, 0);
        }
    }
#pragma unroll
    for (int m = 0; m < 2; m++) {
        float o4[4];
#pragma unroll
        for (int r = 0; r < 4; r++) o4[r] = oacc[m][r];
        *(float4*)&out[(size_t)(tokbase + lc) * 128 + (2 * w + m) * 16 + lr * 4] = *(float4*)o4;
    }
}

// ---------------------------------------------------------------- launch
extern "C" void kernel_launch(void* const* d_in, const int* in_sizes, int n_in,
                              void* d_out, int out_size, void* d_ws, size_t ws_size,
                              hipStream_t stream) {
    const float* x        = (const float*)d_in[0];
    const float* w_in     = (const float*)d_in[1];
    const float* conv_w   = (const float*)d_in[2];
    const float* conv_b   = (const float*)d_in[3];
    const float* x_proj_w = (const float*)d_in[4];
    const float* dt_w     = (const float*)d_in[5];
    const float* dt_b     = (const float*)d_in[6];
    const float* A_logs   = (const float*)d_in[7];
    const float* Ds       = (const float*)d_in[8];
    const float* w_fold   = (const float*)d_in[9];
    const float* ln_g     = (const float*)d_in[10];
    const float* ln_b     = (const float*)d_in[11];
    const float* w_out    = (const float*)d_in[12];
    float* out = (float*)d_out;

    float* ws     = (float*)d_ws;
    float* xpt    = ws;                    // B*256*L        = 2,097,152
    float* zbufT  = xpt    + 2097152;      // B*256*L        = 2,097,152 (ch-major)
    float* xc     = zbufT  + 2097152;      // B*16*L         =   131,072
    float* dts    = xc     + 131072;       // B*14*L         =   114,688
    float* bc2    = dts    + 114688;       // B*32*L bf16    (float-sized slot)
    float* ybuf   = bc2    + 262144;       // B*432*L bf16   (float-sized slot)
    float* wib    = ybuf   + 3538944;      // 512*128 bf16   =    32,768 floats
    float* wfb    = wib    + 32768;        // 256*448 bf16   =    57,344 floats
    float* wob    = wfb    + 57344;        // 128*256 bf16   =    16,384 floats
    float* wxpb   = wob    + 16384;        // 48*448 bf16    =    10,752 floats

    k_wprep<<<dim3(916), dim3(256), 0, stream>>>(w_in, w_fold, w_out, x_proj_w,
                                                 (unsigned short*)wib, (unsigned short*)wfb,
                                                 (unsigned short*)wob, (unsigned short*)wxpb);
    k_inproj<<<dim3(NTOK / 32), dim3(256), 0, stream>>>(x, (const unsigned short*)wib,
                                                        xpt, zbufT);
    k_conv<<<dim3(NTOK / 256, CCONV), dim3(256), 0, stream>>>(xpt, conv_w, conv_b, xc);
    k_xdbl<<<dim3(NTOK / 32), dim3(256), 0, stream>>>(xc, (const unsigned short*)wxpb,
                                                      dts, (__hip_bfloat16*)bc2);
    k_scan<<<dim3(BATCH * DSEQ), dim3(256), 0, stream>>>(xc, dts, (const unsigned short*)bc2,
                                                         dt_w, dt_b, A_logs, Ds,
                                                         (unsigned short*)ybuf);
    k_tail<<<dim3(NTOK / 16), dim3(256), 0, stream>>>((const unsigned short*)ybuf, zbufT,
                                                      (const unsigned short*)wfb, ln_g, ln_b,
                                                      (const unsigned short*)wob, out);
}